// Round 13
// baseline (15787.872 us; speedup 1.0000x reference)
//
#include <hip/hip_runtime.h>
#include <math.h>

#define NL 8
#define SS 512
#define NBROWS 1024
#define NH 32
#define EPSV 1e-5f
#define BS (NBROWS*SS)
#define NBLK 64
#define RPT 2
#define RPB 16               // rows per block = 8 row-groups * RPT
#define GSTRIDE 16           // u64 stride per step slot = 128B line
#define PS 1024.0f           // 2^10 fixed-point scale
#define PSI (1.0/1024.0)
#define Q1LIM ((1ll<<21)-1)  // per-block s1 clamp (64 biased sums < 2^28 field)
#define Q2LIM ((1ll<<23)-1)  // per-block s2 clamp (64 sums < 2^29 field)
#define CNT1 (1ull<<57)      // count increment, field [63:57]

__global__ void zero_ws(unsigned int* __restrict__ f, int n) {
    int i = blockIdx.x * blockDim.x + threadIdx.x;
    if (i < n) f[i] = 0u;
}

__global__ __launch_bounds__(256)
void gru_kernel(const float* __restrict__ xin,
                const float* __restrict__ maxv, const float* __restrict__ minv,
                const float* __restrict__ Wr_w, const float* __restrict__ Wr_b,
                const float* __restrict__ Ur_w, const float* __restrict__ Ur_b,
                const float* __restrict__ Wz_w, const float* __restrict__ Wz_b,
                const float* __restrict__ Uz_w, const float* __restrict__ Uz_b,
                const float* __restrict__ Wh_w, const float* __restrict__ Wh_b,
                const float* __restrict__ Uh_w, const float* __restrict__ Uh_b,
                const float* __restrict__ out_w, const float* __restrict__ out_b,
                const float* __restrict__ bn_g, const float* __restrict__ bn_b,
                float* __restrict__ dout,
                unsigned long long* __restrict__ gsum)   // [4096][GSTRIDE]
{
    const int tid  = threadIdx.x;
    const int j    = tid & 31;     // h column
    const int rg   = tid >> 5;     // row group 0..7
    const int lane = tid & 63;
    const int wid  = tid >> 6;
    const int bid  = blockIdx.x;

    __shared__ float hls[RPB][36];     // rows are half-wave-private
    __shared__ float partials[4][2];
    __shared__ float bcast[2];
    __shared__ unsigned long long stot[2];   // per-parity shared total (LDS relay)

    float myh[RPT];
#pragma unroll
    for (int q = 0; q < RPT; ++q) { hls[rg + 8*q][j] = 0.f; myh[q] = 0.f; }
    if (tid == 0) { stot[0] = 0ull; stot[1] = 0ull; }
    __syncthreads();

    const float dv0 = maxv[0]-minv[0], dv1 = maxv[1]-minv[1];
    const float dv2 = maxv[2]-minv[2], dv3 = maxv[3]-minv[3];
    const float mv0 = minv[0], mv1 = minv[1], mv2 = minv[2], mv3 = minv[3];

    // prefetch x for step 0
    float4 xpre[RPT];
#pragma unroll
    for (int q = 0; q < RPT; ++q)
        xpre[q] = *(const float4*)&xin[(((bid*RPB + rg + 8*q)*SS) + 0)*4];

    for (int l = 0; l < NL; ++l) {
        float ur[NH], uz[NH], uh[NH];
#pragma unroll
        for (int k = 0; k < NH; ++k) {
            ur[k] = Ur_w[(l*NH + k)*NH + j];
            uz[k] = Uz_w[(l*NH + k)*NH + j];
            uh[k] = Uh_w[(l*NH + k)*NH + j];
        }
        float wr[4], wz[4], wh[4];
#pragma unroll
        for (int i = 0; i < 4; ++i) {
            wr[i] = Wr_w[(l*4 + i)*NH + j];
            wz[i] = Wz_w[(l*4 + i)*NH + j];
            wh[i] = Wh_w[(l*4 + i)*NH + j];
        }
        const float brj = Wr_b[l*NH + j] + Ur_b[l*NH + j];
        const float bzj = Wz_b[l*NH + j] + Uz_b[l*NH + j];
        const float bhx = Wh_b[l*NH + j];
        const float bhu = Uh_b[l*NH + j];
        const float wo0 = out_w[(l*NH + j)*4 + 0];
        const float wo1 = out_w[(l*NH + j)*4 + 1];
        const float wo2 = out_w[(l*NH + j)*4 + 2];
        const float wo3 = out_w[(l*NH + j)*4 + 3];
        const float bo0 = out_b[l*4 + 0], bo1 = out_b[l*4 + 1];
        const float bo2 = out_b[l*4 + 2], bo3 = out_b[l*4 + 3];
        const float gg = bn_g[l], bb = bn_b[l];

        for (int s = 0; s < SS; ++s) {
            const int g = l*SS + s;
            const int p = g & 1;

            // issue next step's x at the top: latency drains inside compute phase
            const int sn = (s + 1) & (SS - 1);
            float4 xnew[RPT];
#pragma unroll
            for (int q = 0; q < RPT; ++q)
                xnew[q] = *(const float4*)&xin[(((bid*RPB + rg + 8*q)*SS) + sn)*4];

            float pre[RPT], zz[RPT];
            float s1 = 0.f, s2 = 0.f;
#pragma unroll
            for (int q = 0; q < RPT; ++q) {
                const int r = rg + 8*q;
                const float4 xc = xpre[q];
                float ar = brj, az = bzj, ax = bhx, au = bhu;
                const float4* hp = (const float4*)(&hls[r][0]);
#pragma unroll
                for (int kk = 0; kk < 8; ++kk) {
                    const float4 hv = hp[kk];
                    ar += hv.x*ur[4*kk+0]; az += hv.x*uz[4*kk+0]; au += hv.x*uh[4*kk+0];
                    ar += hv.y*ur[4*kk+1]; az += hv.y*uz[4*kk+1]; au += hv.y*uh[4*kk+1];
                    ar += hv.z*ur[4*kk+2]; az += hv.z*uz[4*kk+2]; au += hv.z*uh[4*kk+2];
                    ar += hv.w*ur[4*kk+3]; az += hv.w*uz[4*kk+3]; au += hv.w*uh[4*kk+3];
                }
                ar += xc.x*wr[0] + xc.y*wr[1] + xc.z*wr[2] + xc.w*wr[3];
                az += xc.x*wz[0] + xc.y*wz[1] + xc.z*wz[2] + xc.w*wz[3];
                ax += xc.x*wh[0] + xc.y*wh[1] + xc.z*wh[2] + xc.w*wh[3];
                const float rr = 1.f/(1.f + expf(-ar));
                zz[q]  = 1.f/(1.f + expf(-az));
                pre[q] = ax + rr*au;
                s1 += pre[q];
                s2 += pre[q]*pre[q];
            }
#pragma unroll
            for (int q = 0; q < RPT; ++q) xpre[q] = xnew[q];

            // deterministic wave butterfly
#pragma unroll
            for (int m = 1; m < 64; m <<= 1) {
                s1 += __shfl_xor(s1, m, 64);
                s2 += __shfl_xor(s2, m, 64);
            }
            if (lane == 0) { partials[wid][0] = s1; partials[wid][1] = s2; }
            __syncthreads();   // barrier 1

            if (wid < 2) {
                unsigned long long tot = 0;
                bool have = false;
                if (wid == 0) {
                    // ---- single fused atomic all-reduce: count | s1 | s2 in one u64 ----
                    unsigned long long addv = 0, old = 0;
                    if (lane == 0) {
                        const float b1 = partials[0][0] + partials[1][0]
                                       + partials[2][0] + partials[3][0];
                        const float b2 = partials[0][1] + partials[1][1]
                                       + partials[2][1] + partials[3][1];
                        long long q1 = llrintf(b1 * PS);
                        long long q2 = llrintf(b2 * PS);
                        q1 = (q1 >  Q1LIM) ?  Q1LIM : ((q1 < -Q1LIM) ? -Q1LIM : q1);
                        q2 = (q2 >  Q2LIM) ?  Q2LIM : ((q2 < 0) ? 0 : q2);
                        addv = CNT1 + ((unsigned long long)(q1 + (1ll<<21)) << 29)
                                    + (unsigned long long)q2;
                        old = __hip_atomic_fetch_add(&gsum[(size_t)g*GSTRIDE], addv,
                                                     __ATOMIC_RELAXED, __HIP_MEMORY_SCOPE_AGENT);
                    }
                    old  = __shfl((long long)old, 0, 64);
                    addv = __shfl((long long)addv, 0, 64);
                    if ((old >> 57) == (unsigned long long)(NBLK - 1)) {
                        // LAST arriver: RMW return holds the totals — no poll; relay via LDS
                        tot = old + addv;
                        have = true;
                        if (lane == 0)
                            __hip_atomic_store(&stot[p], tot, __ATOMIC_RELAXED,
                                               __HIP_MEMORY_SCOPE_WORKGROUP);
                    }
                }
                if (!have) {
                    // two phase-staggered pollers (wave 0 + wave 1); LDS relay for fast exit
                    for (;;) {
                        const unsigned long long lt =
                            __hip_atomic_load(&stot[p], __ATOMIC_RELAXED,
                                              __HIP_MEMORY_SCOPE_WORKGROUP);
                        if ((lt >> 57) == (unsigned long long)NBLK) { tot = lt; break; }
                        const unsigned long long gt =
                            __hip_atomic_load(&gsum[(size_t)g*GSTRIDE], __ATOMIC_RELAXED,
                                              __HIP_MEMORY_SCOPE_AGENT);
                        if ((gt >> 57) == (unsigned long long)NBLK) {
                            tot = gt;
                            if (lane == 0)
                                __hip_atomic_store(&stot[p], gt, __ATOMIC_RELAXED,
                                                   __HIP_MEMORY_SCOPE_WORKGROUP);
                            break;
                        }
                    }
                }
                // unique integer total -> identical floats in every wave (deterministic)
                const long long a1 = (long long)((tot >> 29) & ((1ull<<28)-1))
                                   - ((long long)NBLK << 21);
                const long long a2 = (long long)(tot & ((1ull<<29)-1));
                const float mean = (float)((double)a1 * PSI) * (1.f/32768.f);
                const float msq  = (float)((double)a2 * PSI) * (1.f/32768.f);
                const float var  = msq - mean*mean;
                const float rstd = rsqrtf(var + EPSV);
                if (lane == 0) { bcast[0] = mean; bcast[1] = rstd; }   // both waves: same value
            }
            __syncthreads();   // barrier 2 (last of the step)
            const float mean = bcast[0], rstd = bcast[1];
            // reset parity slot for step g+2 (next read separated by step g+1's barriers)
            if (tid == 0)
                __hip_atomic_store(&stot[p], 0ull, __ATOMIC_RELAXED,
                                   __HIP_MEMORY_SCOPE_WORKGROUP);

#pragma unroll
            for (int q = 0; q < RPT; ++q) {
                const float prop = fmaxf((pre[q] - mean)*rstd*gg + bb, 0.f);
                const float hn   = (1.f - zz[q])*myh[q] + zz[q]*prop;
                myh[q] = hn;
                hls[rg + 8*q][j] = hn;   // half-wave-private row: no end barrier needed
                if (l == NL - 1) {
                    float t0 = hn*wo0, t1o = hn*wo1, t2o = hn*wo2, t3o = hn*wo3;
#pragma unroll
                    for (int m = 1; m < 32; m <<= 1) {
                        t0  += __shfl_xor(t0,  m, 32);
                        t1o += __shfl_xor(t1o, m, 32);
                        t2o += __shfl_xor(t2o, m, 32);
                        t3o += __shfl_xor(t3o, m, 32);
                    }
                    if (j == 0) {
                        const int brow = bid*RPB + rg + 8*q;
                        const int idx  = brow*SS + s;
                        dout[BS + idx*3 + 0] = (t0  + bo0)*dv0 + mv0;   // Irad
                        dout[BS + idx*3 + 1] = (t1o + bo1)*dv1 + mv1;   // Tout
                        dout[BS + idx*3 + 2] = (t2o + bo2)*dv2 + mv2;   // Hair
                        dout[idx]            = (t3o + bo3)*dv3 + mv3;   // Tair init
                    }
                }
            }
        }
    }
}

__device__ __forceinline__ float dydt_f(float Ta, float Tout, float Hair,
                                        float Qsun, float Rn, float rsbase) {
    Ta = fminf(Ta, 500.f);
    const float Qcov = 5.f*(Ta - Tout);
    const float Hs   = 5.5638f*expf(0.0572f*Ta);
    const float ce   = 0.7584f*expf(0.0518f*Ta);
    const float dd   = Ta - 5.f;
    const float rs   = rsbase*(1.f + 0.023f*dd*dd);
    const float ge   = 5.2f/((1.f + ce)*150.f + rs);
    const float Hcrop  = Hs + ce*(150.f/5.2f)*(Rn/2450.f);
    const float Qtrans = ge*(-2450.f)*(Hcrop - Hair);
    const float Qvent  = -369.3375f*(Ta - Tout);
    return (-1.0f/1000.f)*(Qsun - Qcov - Qtrans - Qvent);
}

__global__ void ode_kernel(float* __restrict__ dout) {
    const int idx = blockIdx.x*blockDim.x + threadIdx.x;
    if (idx >= BS) return;
    float Ta = dout[idx];
    const float Irad = dout[BS + idx*3 + 0];
    const float Tout = dout[BS + idx*3 + 1];
    const float Hair = dout[BS + idx*3 + 2];
    const float Qsun = 7.f*Irad;
    const float Rn   = 0.86f*(1.f - expf(-1.82f))*Qsun;
    const float rsbase = 82.f + 570.f*expf(-1e-4f*(Rn/2.6f));
    const float hs = 1.5f;
#pragma unroll 1
    for (int it = 0; it < 40; ++it) {
        const float k1 = dydt_f(Ta, Tout, Hair, Qsun, Rn, rsbase);
        const float k2 = dydt_f(Ta + hs*(0.2f*k1), Tout, Hair, Qsun, Rn, rsbase);
        const float k3 = dydt_f(Ta + hs*(0.075f*k1 + 0.225f*k2), Tout, Hair, Qsun, Rn, rsbase);
        const float k4 = dydt_f(Ta + hs*((44.f/45.f)*k1 - (56.f/15.f)*k2 + (32.f/9.f)*k3),
                                Tout, Hair, Qsun, Rn, rsbase);
        const float k5 = dydt_f(Ta + hs*((19372.f/6561.f)*k1 - (25360.f/2187.f)*k2
                                         + (64448.f/6561.f)*k3 - (212.f/729.f)*k4),
                                Tout, Hair, Qsun, Rn, rsbase);
        const float k6 = dydt_f(Ta + hs*((9017.f/3168.f)*k1 - (355.f/33.f)*k2
                                         + (46732.f/5247.f)*k3 + (49.f/176.f)*k4
                                         - (5103.f/18656.f)*k5),
                                Tout, Hair, Qsun, Rn, rsbase);
        Ta = Ta + hs*((35.f/384.f)*k1 + (500.f/1113.f)*k3 + (125.f/192.f)*k4
                      - (2187.f/6784.f)*k5 + (11.f/84.f)*k6);
    }
    dout[idx] = Ta;
    dout[4*BS + idx] = Ta;
}

extern "C" void kernel_launch(void* const* d_in, const int* in_sizes, int n_in,
                              void* d_out, int out_size, void* d_ws, size_t ws_size,
                              hipStream_t stream) {
    const float* xin   = (const float*)d_in[0];
    const float* maxv  = (const float*)d_in[1];
    const float* minv  = (const float*)d_in[2];
    const float* Wr_w  = (const float*)d_in[3];
    const float* Wr_b  = (const float*)d_in[4];
    const float* Ur_w  = (const float*)d_in[5];
    const float* Ur_b  = (const float*)d_in[6];
    const float* Wz_w  = (const float*)d_in[7];
    const float* Wz_b  = (const float*)d_in[8];
    const float* Uz_w  = (const float*)d_in[9];
    const float* Uz_b  = (const float*)d_in[10];
    const float* Wh_w  = (const float*)d_in[11];
    const float* Wh_b  = (const float*)d_in[12];
    const float* Uh_w  = (const float*)d_in[13];
    const float* Uh_b  = (const float*)d_in[14];
    const float* out_w = (const float*)d_in[15];
    const float* out_b = (const float*)d_in[16];
    const float* bn_g  = (const float*)d_in[17];
    const float* bn_b  = (const float*)d_in[18];
    float* dout = (float*)d_out;

    const int steps = NL*SS;                               // 4096
    unsigned long long* gsum = (unsigned long long*)d_ws;  // [4096][16] u64 (512 KB)
    const int nwords = steps*GSTRIDE*2;                    // u32 words

    zero_ws<<<(nwords + 255)/256, 256, 0, stream>>>((unsigned int*)d_ws, nwords);

    gru_kernel<<<NBLK, 256, 0, stream>>>(xin, maxv, minv,
        Wr_w, Wr_b, Ur_w, Ur_b, Wz_w, Wz_b, Uz_w, Uz_b,
        Wh_w, Wh_b, Uh_w, Uh_b, out_w, out_b, bn_g, bn_b,
        dout, gsum);

    ode_kernel<<<BS/256, 256, 0, stream>>>(dout);
}

// Round 14
// 11916.016 us; speedup vs baseline: 1.3249x; 1.3249x over previous
//
#include <hip/hip_runtime.h>
#include <math.h>

#define NL 8
#define SS 512
#define NBROWS 1024
#define NH 32
#define EPSV 1e-5f
#define BS (NBROWS*SS)
#define NBLK 64
#define RPT 2
#define RPB 16               // rows per block = 8 row-groups * RPT
#define GSTRIDE 16           // u64 stride per step slot = 128B line
#define PS 1024.0f           // 2^10 fixed-point scale
#define PSI (1.0/1024.0)
#define Q1LIM ((1ll<<21)-1)  // per-block s1 clamp (64 biased sums < 2^28 field)
#define Q2LIM ((1ll<<23)-1)  // per-block s2 clamp (64 sums < 2^29 field)
#define CNT1 (1ull<<57)      // count increment, field [63:57]

__global__ void zero_ws(unsigned int* __restrict__ f, int n) {
    int i = blockIdx.x * blockDim.x + threadIdx.x;
    if (i < n) f[i] = 0u;
}

__global__ __launch_bounds__(256)
void gru_kernel(const float* __restrict__ xin,
                const float* __restrict__ maxv, const float* __restrict__ minv,
                const float* __restrict__ Wr_w, const float* __restrict__ Wr_b,
                const float* __restrict__ Ur_w, const float* __restrict__ Ur_b,
                const float* __restrict__ Wz_w, const float* __restrict__ Wz_b,
                const float* __restrict__ Uz_w, const float* __restrict__ Uz_b,
                const float* __restrict__ Wh_w, const float* __restrict__ Wh_b,
                const float* __restrict__ Uh_w, const float* __restrict__ Uh_b,
                const float* __restrict__ out_w, const float* __restrict__ out_b,
                const float* __restrict__ bn_g, const float* __restrict__ bn_b,
                float* __restrict__ dout,
                unsigned long long* __restrict__ gsum)   // [4096][GSTRIDE]
{
    const int tid  = threadIdx.x;
    const int j    = tid & 31;     // h column
    const int rg   = tid >> 5;     // row group 0..7
    const int lane = tid & 63;
    const int wid  = tid >> 6;
    const int bid  = blockIdx.x;

    __shared__ float hls[RPB][36];     // rows are half-wave-private
    __shared__ float partials[4][2];
    __shared__ float bcast[2];

    float myh[RPT];
#pragma unroll
    for (int q = 0; q < RPT; ++q) { hls[rg + 8*q][j] = 0.f; myh[q] = 0.f; }
    __syncthreads();

    const float dv0 = maxv[0]-minv[0], dv1 = maxv[1]-minv[1];
    const float dv2 = maxv[2]-minv[2], dv3 = maxv[3]-minv[3];
    const float mv0 = minv[0], mv1 = minv[1], mv2 = minv[2], mv3 = minv[3];

    // prefetch x for step 0
    float4 xpre[RPT];
#pragma unroll
    for (int q = 0; q < RPT; ++q)
        xpre[q] = *(const float4*)&xin[(((bid*RPB + rg + 8*q)*SS) + 0)*4];

    for (int l = 0; l < NL; ++l) {
        float ur[NH], uz[NH], uh[NH];
#pragma unroll
        for (int k = 0; k < NH; ++k) {
            ur[k] = Ur_w[(l*NH + k)*NH + j];
            uz[k] = Uz_w[(l*NH + k)*NH + j];
            uh[k] = Uh_w[(l*NH + k)*NH + j];
        }
        float wr[4], wz[4], wh[4];
#pragma unroll
        for (int i = 0; i < 4; ++i) {
            wr[i] = Wr_w[(l*4 + i)*NH + j];
            wz[i] = Wz_w[(l*4 + i)*NH + j];
            wh[i] = Wh_w[(l*4 + i)*NH + j];
        }
        const float brj = Wr_b[l*NH + j] + Ur_b[l*NH + j];
        const float bzj = Wz_b[l*NH + j] + Uz_b[l*NH + j];
        const float bhx = Wh_b[l*NH + j];
        const float bhu = Uh_b[l*NH + j];
        const float wo0 = out_w[(l*NH + j)*4 + 0];
        const float wo1 = out_w[(l*NH + j)*4 + 1];
        const float wo2 = out_w[(l*NH + j)*4 + 2];
        const float wo3 = out_w[(l*NH + j)*4 + 3];
        const float bo0 = out_b[l*4 + 0], bo1 = out_b[l*4 + 1];
        const float bo2 = out_b[l*4 + 2], bo3 = out_b[l*4 + 3];
        const float gg = bn_g[l], bb = bn_b[l];

        for (int s = 0; s < SS; ++s) {
            const int g = l*SS + s;

            // issue next step's x at the top: latency drains inside compute phase
            const int sn = (s + 1) & (SS - 1);
            float4 xnew[RPT];
#pragma unroll
            for (int q = 0; q < RPT; ++q)
                xnew[q] = *(const float4*)&xin[(((bid*RPB + rg + 8*q)*SS) + sn)*4];

            float pre[RPT], zz[RPT];
            float s1 = 0.f, s2 = 0.f;
#pragma unroll
            for (int q = 0; q < RPT; ++q) {
                const int r = rg + 8*q;
                const float4 xc = xpre[q];
                float ar = brj, az = bzj, ax = bhx, au = bhu;
                const float4* hp = (const float4*)(&hls[r][0]);
#pragma unroll
                for (int kk = 0; kk < 8; ++kk) {
                    const float4 hv = hp[kk];
                    ar += hv.x*ur[4*kk+0]; az += hv.x*uz[4*kk+0]; au += hv.x*uh[4*kk+0];
                    ar += hv.y*ur[4*kk+1]; az += hv.y*uz[4*kk+1]; au += hv.y*uh[4*kk+1];
                    ar += hv.z*ur[4*kk+2]; az += hv.z*uz[4*kk+2]; au += hv.z*uh[4*kk+2];
                    ar += hv.w*ur[4*kk+3]; az += hv.w*uz[4*kk+3]; au += hv.w*uh[4*kk+3];
                }
                ar += xc.x*wr[0] + xc.y*wr[1] + xc.z*wr[2] + xc.w*wr[3];
                az += xc.x*wz[0] + xc.y*wz[1] + xc.z*wz[2] + xc.w*wz[3];
                ax += xc.x*wh[0] + xc.y*wh[1] + xc.z*wh[2] + xc.w*wh[3];
                const float rr = 1.f/(1.f + expf(-ar));
                zz[q]  = 1.f/(1.f + expf(-az));
                pre[q] = ax + rr*au;
                s1 += pre[q];
                s2 += pre[q]*pre[q];
            }
#pragma unroll
            for (int q = 0; q < RPT; ++q) xpre[q] = xnew[q];

            // deterministic wave butterfly
#pragma unroll
            for (int m = 1; m < 64; m <<= 1) {
                s1 += __shfl_xor(s1, m, 64);
                s2 += __shfl_xor(s2, m, 64);
            }
            if (lane == 0) { partials[wid][0] = s1; partials[wid][1] = s2; }
            __syncthreads();   // barrier 1

            if (wid == 0) {
                // ---- single fused atomic all-reduce: count | s1 | s2 in one u64 ----
                unsigned long long addv = 0, old = 0;
                if (lane == 0) {
                    const float b1 = partials[0][0] + partials[1][0] + partials[2][0] + partials[3][0];
                    const float b2 = partials[0][1] + partials[1][1] + partials[2][1] + partials[3][1];
                    long long q1 = llrintf(b1 * PS);
                    long long q2 = llrintf(b2 * PS);
                    q1 = (q1 >  Q1LIM) ?  Q1LIM : ((q1 < -Q1LIM) ? -Q1LIM : q1);
                    q2 = (q2 >  Q2LIM) ?  Q2LIM : ((q2 < 0) ? 0 : q2);
                    addv = CNT1 + ((unsigned long long)(q1 + (1ll<<21)) << 29)
                                + (unsigned long long)q2;
                    old = __hip_atomic_fetch_add(&gsum[(size_t)g*GSTRIDE], addv,
                                                 __ATOMIC_RELAXED, __HIP_MEMORY_SCOPE_AGENT);
                }
                old  = __shfl((long long)old, 0, 64);
                addv = __shfl((long long)addv, 0, 64);

                unsigned long long tot;
                if ((old >> 57) == (unsigned long long)(NBLK - 1)) {
                    // LAST arriver: RMW return already holds the complete totals — no poll.
                    tot = old + addv;
                } else {
                    // poll gsum directly: the winning load IS the data (count==64 in top bits)
                    for (;;) {
                        tot = __hip_atomic_load(&gsum[(size_t)g*GSTRIDE],
                                                __ATOMIC_RELAXED, __HIP_MEMORY_SCOPE_AGENT);
                        if ((tot >> 57) == (unsigned long long)NBLK) break;
                    }
                }
                // unique integer total -> identical floats in every block (deterministic)
                const long long a1 = (long long)((tot >> 29) & ((1ull<<28)-1))
                                   - ((long long)NBLK << 21);
                const long long a2 = (long long)(tot & ((1ull<<29)-1));
                const float mean = (float)((double)a1 * PSI) * (1.f/32768.f);
                const float msq  = (float)((double)a2 * PSI) * (1.f/32768.f);
                const float var  = msq - mean*mean;
                const float rstd = rsqrtf(var + EPSV);
                if (lane == 0) { bcast[0] = mean; bcast[1] = rstd; }
            }
            __syncthreads();   // barrier 2 (last of the step)
            const float mean = bcast[0], rstd = bcast[1];

#pragma unroll
            for (int q = 0; q < RPT; ++q) {
                const float prop = fmaxf((pre[q] - mean)*rstd*gg + bb, 0.f);
                const float hn   = (1.f - zz[q])*myh[q] + zz[q]*prop;
                myh[q] = hn;
                hls[rg + 8*q][j] = hn;   // half-wave-private row: no end barrier needed
                if (l == NL - 1) {
                    float t0 = hn*wo0, t1o = hn*wo1, t2o = hn*wo2, t3o = hn*wo3;
#pragma unroll
                    for (int m = 1; m < 32; m <<= 1) {
                        t0  += __shfl_xor(t0,  m, 32);
                        t1o += __shfl_xor(t1o, m, 32);
                        t2o += __shfl_xor(t2o, m, 32);
                        t3o += __shfl_xor(t3o, m, 32);
                    }
                    if (j == 0) {
                        const int brow = bid*RPB + rg + 8*q;
                        const int idx  = brow*SS + s;
                        dout[BS + idx*3 + 0] = (t0  + bo0)*dv0 + mv0;   // Irad
                        dout[BS + idx*3 + 1] = (t1o + bo1)*dv1 + mv1;   // Tout
                        dout[BS + idx*3 + 2] = (t2o + bo2)*dv2 + mv2;   // Hair
                        dout[idx]            = (t3o + bo3)*dv3 + mv3;   // Tair init
                    }
                }
            }
        }
    }
}

__device__ __forceinline__ float dydt_f(float Ta, float Tout, float Hair,
                                        float Qsun, float Rn, float rsbase) {
    Ta = fminf(Ta, 500.f);
    const float Qcov = 5.f*(Ta - Tout);
    const float Hs   = 5.5638f*expf(0.0572f*Ta);
    const float ce   = 0.7584f*expf(0.0518f*Ta);
    const float dd   = Ta - 5.f;
    const float rs   = rsbase*(1.f + 0.023f*dd*dd);
    const float ge   = 5.2f/((1.f + ce)*150.f + rs);
    const float Hcrop  = Hs + ce*(150.f/5.2f)*(Rn/2450.f);
    const float Qtrans = ge*(-2450.f)*(Hcrop - Hair);
    const float Qvent  = -369.3375f*(Ta - Tout);
    return (-1.0f/1000.f)*(Qsun - Qcov - Qtrans - Qvent);
}

__global__ void ode_kernel(float* __restrict__ dout) {
    const int idx = blockIdx.x*blockDim.x + threadIdx.x;
    if (idx >= BS) return;
    float Ta = dout[idx];
    const float Irad = dout[BS + idx*3 + 0];
    const float Tout = dout[BS + idx*3 + 1];
    const float Hair = dout[BS + idx*3 + 2];
    const float Qsun = 7.f*Irad;
    const float Rn   = 0.86f*(1.f - expf(-1.82f))*Qsun;
    const float rsbase = 82.f + 570.f*expf(-1e-4f*(Rn/2.6f));
    const float hs = 1.5f;
#pragma unroll 1
    for (int it = 0; it < 40; ++it) {
        const float k1 = dydt_f(Ta, Tout, Hair, Qsun, Rn, rsbase);
        const float k2 = dydt_f(Ta + hs*(0.2f*k1), Tout, Hair, Qsun, Rn, rsbase);
        const float k3 = dydt_f(Ta + hs*(0.075f*k1 + 0.225f*k2), Tout, Hair, Qsun, Rn, rsbase);
        const float k4 = dydt_f(Ta + hs*((44.f/45.f)*k1 - (56.f/15.f)*k2 + (32.f/9.f)*k3),
                                Tout, Hair, Qsun, Rn, rsbase);
        const float k5 = dydt_f(Ta + hs*((19372.f/6561.f)*k1 - (25360.f/2187.f)*k2
                                         + (64448.f/6561.f)*k3 - (212.f/729.f)*k4),
                                Tout, Hair, Qsun, Rn, rsbase);
        const float k6 = dydt_f(Ta + hs*((9017.f/3168.f)*k1 - (355.f/33.f)*k2
                                         + (46732.f/5247.f)*k3 + (49.f/176.f)*k4
                                         - (5103.f/18656.f)*k5),
                                Tout, Hair, Qsun, Rn, rsbase);
        Ta = Ta + hs*((35.f/384.f)*k1 + (500.f/1113.f)*k3 + (125.f/192.f)*k4
                      - (2187.f/6784.f)*k5 + (11.f/84.f)*k6);
    }
    dout[idx] = Ta;
    dout[4*BS + idx] = Ta;
}

extern "C" void kernel_launch(void* const* d_in, const int* in_sizes, int n_in,
                              void* d_out, int out_size, void* d_ws, size_t ws_size,
                              hipStream_t stream) {
    const float* xin   = (const float*)d_in[0];
    const float* maxv  = (const float*)d_in[1];
    const float* minv  = (const float*)d_in[2];
    const float* Wr_w  = (const float*)d_in[3];
    const float* Wr_b  = (const float*)d_in[4];
    const float* Ur_w  = (const float*)d_in[5];
    const float* Ur_b  = (const float*)d_in[6];
    const float* Wz_w  = (const float*)d_in[7];
    const float* Wz_b  = (const float*)d_in[8];
    const float* Uz_w  = (const float*)d_in[9];
    const float* Uz_b  = (const float*)d_in[10];
    const float* Wh_w  = (const float*)d_in[11];
    const float* Wh_b  = (const float*)d_in[12];
    const float* Uh_w  = (const float*)d_in[13];
    const float* Uh_b  = (const float*)d_in[14];
    const float* out_w = (const float*)d_in[15];
    const float* out_b = (const float*)d_in[16];
    const float* bn_g  = (const float*)d_in[17];
    const float* bn_b  = (const float*)d_in[18];
    float* dout = (float*)d_out;

    const int steps = NL*SS;                               // 4096
    unsigned long long* gsum = (unsigned long long*)d_ws;  // [4096][16] u64 (512 KB)
    const int nwords = steps*GSTRIDE*2;                    // u32 words

    zero_ws<<<(nwords + 255)/256, 256, 0, stream>>>((unsigned int*)d_ws, nwords);

    gru_kernel<<<NBLK, 256, 0, stream>>>(xin, maxv, minv,
        Wr_w, Wr_b, Ur_w, Ur_b, Wz_w, Wz_b, Uz_w, Uz_b,
        Wh_w, Wh_b, Uh_w, Uh_b, out_w, out_b, bn_g, bn_b,
        dout, gsum);

    ode_kernel<<<BS/256, 256, 0, stream>>>(dout);
}